// Round 1
// baseline (928.017 us; speedup 1.0000x reference)
//
#include <hip/hip_runtime.h>
#include <stdint.h>

#define HEADS 16
#define BSZ 512
#define NTOK 65
#define MTOK (BSZ * NTOK)   // 33280 = 260*128
#define NX  34078720UL      // x elems
#define NQW 3145728UL       // w_qkv elems
#define NPW 1048576UL       // w_proj elems

typedef __attribute__((ext_vector_type(8))) short bf16x8;
typedef __attribute__((ext_vector_type(4))) float f32x4;

__device__ __forceinline__ unsigned short f2bf(float f) {
  unsigned u = __float_as_uint(f);
  u += 0x7FFFu + ((u >> 16) & 1u);          // RNE
  return (unsigned short)(u >> 16);
}
__device__ __forceinline__ float bf2f(unsigned short h) {
  return __uint_as_float(((unsigned)h) << 16);
}

// ---------------- fp32 -> bf16 cast of x, w_qkv, w_proj ----------------
__global__ __launch_bounds__(256) void cast3_kernel(
    const float* __restrict__ x, const float* __restrict__ wq, const float* __restrict__ wp,
    unsigned short* __restrict__ xb, unsigned short* __restrict__ wqb, unsigned short* __restrict__ wpb) {
  size_t u = ((size_t)blockIdx.x * 256 + threadIdx.x) * 4;
  const float* src; unsigned short* dst; size_t off;
  if (u < NX)            { src = x;  dst = xb;  off = u; }
  else if (u < NX + NQW) { src = wq; dst = wqb; off = u - NX; }
  else                   { src = wp; dst = wpb; off = u - NX - NQW; }
  float4 v = *(const float4*)(src + off);
  ushort4 o;
  o.x = f2bf(v.x); o.y = f2bf(v.y); o.z = f2bf(v.z); o.w = f2bf(v.w);
  *(ushort4*)(dst + off) = o;
}

// ---------------- bf16 GEMM  C = A[M,1024] @ B[N,1024]^T ----------------
// 128x128 tile, 256 thr (4 waves, each 64x64 as 4x4 of 16x16x32 MFMA).
// LDS tiles stored as 16B chunks with chunk-XOR swizzle (c' = k8 ^ (row&7))
// so ds_read_b128 fragment reads are bank-conflict-free.
// MODE 0: epilogue scatters qkv -> q[BH,65,64], k[BH,65,64], vT[BH,64,80] (bf16)
// MODE 1: epilogue writes fp32 to out[M,1024]
template <int MODE>
__global__ __launch_bounds__(256) void gemm_bt_kernel(
    const unsigned short* __restrict__ A, const unsigned short* __restrict__ Bm,
    unsigned short* __restrict__ qws, unsigned short* __restrict__ kws,
    unsigned short* __restrict__ vws, float* __restrict__ outp) {
  __shared__ unsigned short As[128 * 64];
  __shared__ unsigned short Bs[128 * 64];
  const int tid = threadIdx.x;
  const int wid = tid >> 6, lane = tid & 63;
  const int lrow = lane & 15, lk = lane >> 4;
  const int bm = blockIdx.y, bn = blockIdx.x;
  const int wr = (wid >> 1) * 64, wc = (wid & 1) * 64;
  const size_t arow0 = (size_t)bm * 128, brow0 = (size_t)bn * 128;

  f32x4 acc[4][4] = {};

  for (int kt = 0; kt < 16; ++kt) {
    __syncthreads();
    const int k0 = kt * 64;
#pragma unroll
    for (int j = 0; j < 4; ++j) {
      int ci = j * 256 + tid;              // chunk 0..1023
      int row = ci >> 3, k8s = ci & 7;
      int k8 = k8s ^ (row & 7);            // logical k-chunk stored at slot k8s
      const unsigned short* srcA = A + (arow0 + row) * 1024 + k0 + k8 * 8;
      __builtin_amdgcn_global_load_lds(
          (const __attribute__((address_space(1))) unsigned int*)srcA,
          (__attribute__((address_space(3))) unsigned int*)As + (size_t)(j * 256 + wid * 64) * 4,
          16, 0, 0);
      const unsigned short* srcB = Bm + (brow0 + row) * 1024 + k0 + k8 * 8;
      __builtin_amdgcn_global_load_lds(
          (const __attribute__((address_space(1))) unsigned int*)srcB,
          (__attribute__((address_space(3))) unsigned int*)Bs + (size_t)(j * 256 + wid * 64) * 4,
          16, 0, 0);
    }
    __syncthreads();
#pragma unroll
    for (int kk = 0; kk < 2; ++kk) {
      const int cpos = (kk * 4 + lk) ^ (lrow & 7);
      bf16x8 af[4], bfv[4];
#pragma unroll
      for (int mt = 0; mt < 4; ++mt)
        af[mt] = *(const bf16x8*)&As[(wr + mt * 16 + lrow) * 64 + cpos * 8];
#pragma unroll
      for (int nt = 0; nt < 4; ++nt)
        bfv[nt] = *(const bf16x8*)&Bs[(wc + nt * 16 + lrow) * 64 + cpos * 8];
#pragma unroll
      for (int mt = 0; mt < 4; ++mt)
#pragma unroll
        for (int nt = 0; nt < 4; ++nt)
          acc[mt][nt] = __builtin_amdgcn_mfma_f32_16x16x32_bf16(af[mt], bfv[nt], acc[mt][nt], 0, 0, 0);
    }
  }

  if (MODE == 0) {
#pragma unroll
    for (int mt = 0; mt < 4; ++mt)
#pragma unroll
      for (int nt = 0; nt < 4; ++nt)
#pragma unroll
        for (int r = 0; r < 4; ++r) {
          int grow = bm * 128 + wr + mt * 16 + lk * 4 + r;   // token
          int gcol = bn * 128 + wc + nt * 16 + lrow;          // d in [0,3072)
          unsigned short bv = f2bf(acc[mt][nt][r]);
          int b = grow / 65, nn = grow - b * 65;
          int sec = gcol >> 10, dl = gcol & 1023;
          int h = dl >> 6, dh = dl & 63;
          size_t bh = (size_t)b * HEADS + h;
          if (sec == 0)      qws[(bh * 65 + nn) * 64 + dh] = bv;
          else if (sec == 1) kws[(bh * 65 + nn) * 64 + dh] = bv;
          else               vws[(bh * 64 + dh) * 80 + nn] = bv;   // transposed
        }
  } else {
#pragma unroll
    for (int mt = 0; mt < 4; ++mt)
#pragma unroll
      for (int nt = 0; nt < 4; ++nt)
#pragma unroll
        for (int r = 0; r < 4; ++r) {
          int grow = bm * 128 + wr + mt * 16 + lk * 4 + r;
          int gcol = bn * 128 + wc + nt * 16 + lrow;
          outp[(size_t)grow * 1024 + gcol] = acc[mt][nt][r];
        }
  }
}

// ---------------- fused LN + attention per (b,h) ----------------
// Pads N 65->80 rows (zeros). S via 16x16x32 MFMA, softmax in-wave,
// P staged to LDS (A-operand swizzled layout, k padded to 96), O = P@V.
__global__ __launch_bounds__(256) void attn_kernel(
    const unsigned short* __restrict__ qws, const unsigned short* __restrict__ kws,
    const unsigned short* __restrict__ vws,
    const float* __restrict__ qn_w, const float* __restrict__ qn_b,
    const float* __restrict__ kn_w, const float* __restrict__ kn_b,
    const float* __restrict__ bias, const float* __restrict__ bias_scale,
    unsigned short* __restrict__ aws) {
  __shared__ unsigned short q_s[80 * 64];    // 8 chunks/row, swizzled
  __shared__ unsigned short k_s[80 * 64];
  __shared__ unsigned short v_s[64 * 128];   // 16 chunks/row (k-dim m padded to 96+)
  __shared__ unsigned short p_s[80 * 128];
  const int tid = threadIdx.x;
  const int bh = blockIdx.x;
  const int b = bh >> 4, h = bh & 15;
  const size_t qbase = (size_t)bh * 65 * 64;
  const size_t vbase = (size_t)bh * 64 * 80;

  // zero P (covers k-pad chunks read by the PV MFMA)
  {
    bf16x8 z = {};
    for (int i = tid; i < 1280; i += 256) *(bf16x8*)&p_s[i * 8] = z;
  }
  // stage q,k (rows >=65 zero)
  for (int ci = tid; ci < 640; ci += 256) {
    int row = ci >> 3, k8s = ci & 7;
    int k8 = k8s ^ (row & 7);
    bf16x8 vq = {}, vk = {};
    if (row < 65) {
      vq = *(const bf16x8*)&qws[qbase + row * 64 + k8 * 8];
      vk = *(const bf16x8*)&kws[qbase + row * 64 + k8 * 8];
    }
    *(bf16x8*)&q_s[row * 64 + k8s * 8] = vq;
    *(bf16x8*)&k_s[row * 64 + k8s * 8] = vk;
  }
  // stage vT (m cols >=65 zero)
  for (int ci = tid; ci < 1024; ci += 256) {
    int d = ci >> 4, cs = ci & 15;
    int c = cs ^ (d & 7);
    bf16x8 vv = {};
    if (c < 8)       vv = *(const bf16x8*)&vws[vbase + d * 80 + c * 8];
    else if (c == 8) vv[0] = (short)vws[vbase + d * 80 + 64];
    *(bf16x8*)&v_s[d * 128 + cs * 8] = vv;
  }
  __syncthreads();

  // LayerNorm in LDS: threads 0..64 -> q rows, 65..129 -> k rows
  if (tid < 130) {
    const int isK = tid >= 65;
    const int row = isK ? tid - 65 : tid;
    unsigned short* base = isK ? k_s : q_s;
    const float* w = isK ? kn_w : qn_w;
    const float* bb = isK ? kn_b : qn_b;
    const int sw = row & 7;
    float sum = 0.f, sum2 = 0.f;
#pragma unroll
    for (int c8 = 0; c8 < 8; ++c8) {
      bf16x8 ch = *(const bf16x8*)&base[row * 64 + (c8 ^ sw) * 8];
#pragma unroll
      for (int j = 0; j < 8; ++j) {
        float f = bf2f((unsigned short)ch[j]);
        sum += f; sum2 += f * f;
      }
    }
    float mu = sum * 0.015625f;
    float var = sum2 * 0.015625f - mu * mu;
    float rstd = rsqrtf(var + 1e-5f);
    float sc = isK ? 1.0f : 0.125f;   // q gets head_dim^-0.5
#pragma unroll
    for (int c8 = 0; c8 < 8; ++c8) {
      bf16x8 ch = *(const bf16x8*)&base[row * 64 + (c8 ^ sw) * 8];
#pragma unroll
      for (int j = 0; j < 8; ++j) {
        int k = c8 * 8 + j;
        float f = bf2f((unsigned short)ch[j]);
        f = ((f - mu) * rstd * w[k] + bb[k]) * sc;
        ch[j] = (short)f2bf(f);
      }
      *(bf16x8*)&base[row * 64 + (c8 ^ sw) * 8] = ch;
    }
  }
  __syncthreads();

  const int wid = tid >> 6, lane = tid & 63;
  const int lrow = lane & 15, lk = lane >> 4;
  const float bsc = *bias_scale;

  // S = q@k^T (+bias, mask, softmax) per 16-row strip; wave w -> strips {w, w==0?4}
  for (int s = wid; s < 5; s += 4) {
    f32x4 accs[5] = {};
#pragma unroll
    for (int kk = 0; kk < 2; ++kk) {
      const int cpos = (kk * 4 + lk) ^ (lrow & 7);
      bf16x8 af = *(const bf16x8*)&q_s[(s * 16 + lrow) * 64 + cpos * 8];
#pragma unroll
      for (int nt = 0; nt < 5; ++nt) {
        bf16x8 bv = *(const bf16x8*)&k_s[(nt * 16 + lrow) * 64 + cpos * 8];
        accs[nt] = __builtin_amdgcn_mfma_f32_16x16x32_bf16(af, bv, accs[nt], 0, 0, 0);
      }
    }
#pragma unroll
    for (int r = 0; r < 4; ++r) {
      int row = s * 16 + lk * 4 + r;     // q token (pad rows computed, not stored)
      int brow = row > 64 ? 64 : row;
      float vals[5];
#pragma unroll
      for (int nt = 0; nt < 5; ++nt) {
        int col = nt * 16 + lrow;        // k token
        float v = accs[nt][r];
        if (col < 65) v += bias[((size_t)h * 65 + brow) * 65 + col] * bsc;
        else v = -1e30f;
        vals[nt] = v;
      }
      float m = vals[0];
#pragma unroll
      for (int nt = 1; nt < 5; ++nt) m = fmaxf(m, vals[nt]);
      m = fmaxf(m, __shfl_xor(m, 1)); m = fmaxf(m, __shfl_xor(m, 2));
      m = fmaxf(m, __shfl_xor(m, 4)); m = fmaxf(m, __shfl_xor(m, 8));
      float ssum = 0.f;
#pragma unroll
      for (int nt = 0; nt < 5; ++nt) { vals[nt] = __expf(vals[nt] - m); ssum += vals[nt]; }
      ssum += __shfl_xor(ssum, 1); ssum += __shfl_xor(ssum, 2);
      ssum += __shfl_xor(ssum, 4); ssum += __shfl_xor(ssum, 8);
      float inv = 1.0f / ssum;
#pragma unroll
      for (int nt = 0; nt < 5; ++nt) {
        int col = nt * 16 + lrow;
        p_s[row * 128 + ((col >> 3) ^ (row & 7)) * 8 + (col & 7)] = f2bf(vals[nt] * inv);
      }
    }
  }
  __syncthreads();

  // O = P @ V  (k-dim 96 with zero pad), write [B*N, 1024] bf16
  const size_t obase = (size_t)b * 65 * 1024 + h * 64;
  for (int s = wid; s < 5; s += 4) {
    f32x4 acco[4] = {};
#pragma unroll
    for (int kk = 0; kk < 3; ++kk) {
      const int cpos = (kk * 4 + lk) ^ (lrow & 7);
      bf16x8 af = *(const bf16x8*)&p_s[(s * 16 + lrow) * 128 + cpos * 8];
#pragma unroll
      for (int nt = 0; nt < 4; ++nt) {
        bf16x8 bv = *(const bf16x8*)&v_s[(nt * 16 + lrow) * 128 + cpos * 8];
        acco[nt] = __builtin_amdgcn_mfma_f32_16x16x32_bf16(af, bv, acco[nt], 0, 0, 0);
      }
    }
#pragma unroll
    for (int r = 0; r < 4; ++r) {
      int row = s * 16 + lk * 4 + r;
      if (row < 65) {
#pragma unroll
        for (int nt = 0; nt < 4; ++nt)
          aws[obase + (size_t)row * 1024 + nt * 16 + lrow] = f2bf(acco[nt][r]);
      }
    }
  }
}

extern "C" void kernel_launch(void* const* d_in, const int* in_sizes, int n_in,
                              void* d_out, int out_size, void* d_ws, size_t ws_size,
                              hipStream_t stream) {
  const float* x     = (const float*)d_in[0];
  const float* wqkv  = (const float*)d_in[1];
  const float* wproj = (const float*)d_in[2];
  const float* qn_w  = (const float*)d_in[3];
  const float* qn_b  = (const float*)d_in[4];
  const float* kn_w  = (const float*)d_in[5];
  const float* kn_b  = (const float*)d_in[6];
  const float* bias  = (const float*)d_in[7];
  const float* bsc   = (const float*)d_in[8];
  float* out = (float*)d_out;

  unsigned short* xb  = (unsigned short*)d_ws;
  unsigned short* wqb = xb + NX;
  unsigned short* wpb = wqb + NQW;
  unsigned short* qws = wpb + NPW;
  unsigned short* kws = qws + 34078720UL;          // BH*65*64
  unsigned short* vws = kws + 34078720UL;
  unsigned short* aws = vws + 41943040UL;          // BH*64*80

  cast3_kernel<<<37376, 256, 0, stream>>>(x, wqkv, wproj, xb, wqb, wpb);
  gemm_bt_kernel<0><<<dim3(24, 260), 256, 0, stream>>>(xb, wqb, qws, kws, vws, nullptr);
  attn_kernel<<<8192, 256, 0, stream>>>(qws, kws, vws, qn_w, qn_b, kn_w, kn_b, bias, bsc, aws);
  gemm_bt_kernel<1><<<dim3(8, 260), 256, 0, stream>>>(aws, wpb, nullptr, nullptr, nullptr, out);
}

// Round 2
// 869.161 us; speedup vs baseline: 1.0677x; 1.0677x over previous
//
#include <hip/hip_runtime.h>
#include <stdint.h>

#define HEADS 16
#define BSZ 512
#define NTOK 65
#define MTOK (BSZ * NTOK)   // 33280 = 260*128
#define NX  34078720UL      // x elems
#define NQW 3145728UL       // w_qkv elems
#define NPW 1048576UL       // w_proj elems

typedef __attribute__((ext_vector_type(8))) short bf16x8;
typedef __attribute__((ext_vector_type(4))) float f32x4;

__device__ __forceinline__ unsigned short f2bf(float f) {
  unsigned u = __float_as_uint(f);
  u += 0x7FFFu + ((u >> 16) & 1u);          // RNE
  return (unsigned short)(u >> 16);
}

// ---------------- fp32 -> bf16 cast of x, w_qkv, w_proj ----------------
__global__ __launch_bounds__(256) void cast3_kernel(
    const float* __restrict__ x, const float* __restrict__ wq, const float* __restrict__ wp,
    unsigned short* __restrict__ xb, unsigned short* __restrict__ wqb, unsigned short* __restrict__ wpb) {
  size_t u = ((size_t)blockIdx.x * 256 + threadIdx.x) * 4;
  const float* src; unsigned short* dst; size_t off;
  if (u < NX)            { src = x;  dst = xb;  off = u; }
  else if (u < NX + NQW) { src = wq; dst = wqb; off = u - NX; }
  else                   { src = wp; dst = wpb; off = u - NX - NQW; }
  float4 v = *(const float4*)(src + off);
  ushort4 o;
  o.x = f2bf(v.x); o.y = f2bf(v.y); o.z = f2bf(v.z); o.w = f2bf(v.w);
  *(ushort4*)(dst + off) = o;
}

// ---------------- bf16 GEMM  C = A[M,1024] @ B[N,1024]^T ----------------
// 128x128 tile, 256 thr (4 waves, each 64x64 as 4x4 of 16x16x32 MFMA).
// LDS tiles stored as 16B chunks with chunk-XOR swizzle (c' = k8 ^ (row&7)).
// MODE 0: epilogue applies fused LayerNorm (q: *0.125) in fp32 via quarter-wave
//         shuffle reduce, scatters q[BH,65,64], k[BH,65,64], vT[BH,64,80] bf16.
//         sec (q/k/v) and head are block/wave-uniform -> cheap addressing.
// MODE 1: epilogue writes fp32 to out[M,1024]
template <int MODE>
__global__ __launch_bounds__(256) void gemm_bt_kernel(
    const unsigned short* __restrict__ A, const unsigned short* __restrict__ Bm,
    unsigned short* __restrict__ qws, unsigned short* __restrict__ kws,
    unsigned short* __restrict__ vws, float* __restrict__ outp,
    const float* __restrict__ qn_w, const float* __restrict__ qn_b,
    const float* __restrict__ kn_w, const float* __restrict__ kn_b) {
  __shared__ unsigned short As[128 * 64];
  __shared__ unsigned short Bs[128 * 64];
  const int tid = threadIdx.x;
  const int wid = tid >> 6, lane = tid & 63;
  const int lrow = lane & 15, lk = lane >> 4;
  const int bm = blockIdx.y, bn = blockIdx.x;
  const int wr = (wid >> 1) * 64, wc = (wid & 1) * 64;
  const size_t arow0 = (size_t)bm * 128, brow0 = (size_t)bn * 128;

  f32x4 acc[4][4] = {};

  for (int kt = 0; kt < 16; ++kt) {
    __syncthreads();
    const int k0 = kt * 64;
#pragma unroll
    for (int j = 0; j < 4; ++j) {
      int ci = j * 256 + tid;              // chunk 0..1023
      int row = ci >> 3, k8s = ci & 7;
      int k8 = k8s ^ (row & 7);            // logical k-chunk stored at slot k8s
      const unsigned short* srcA = A + (arow0 + row) * 1024 + k0 + k8 * 8;
      __builtin_amdgcn_global_load_lds(
          (const __attribute__((address_space(1))) unsigned int*)srcA,
          (__attribute__((address_space(3))) unsigned int*)As + (size_t)(j * 256 + wid * 64) * 4,
          16, 0, 0);
      const unsigned short* srcB = Bm + (brow0 + row) * 1024 + k0 + k8 * 8;
      __builtin_amdgcn_global_load_lds(
          (const __attribute__((address_space(1))) unsigned int*)srcB,
          (__attribute__((address_space(3))) unsigned int*)Bs + (size_t)(j * 256 + wid * 64) * 4,
          16, 0, 0);
    }
    __syncthreads();
#pragma unroll
    for (int kk = 0; kk < 2; ++kk) {
      const int cpos = (kk * 4 + lk) ^ (lrow & 7);
      bf16x8 af[4], bfv[4];
#pragma unroll
      for (int mt = 0; mt < 4; ++mt)
        af[mt] = *(const bf16x8*)&As[(wr + mt * 16 + lrow) * 64 + cpos * 8];
#pragma unroll
      for (int nt = 0; nt < 4; ++nt)
        bfv[nt] = *(const bf16x8*)&Bs[(wc + nt * 16 + lrow) * 64 + cpos * 8];
#pragma unroll
      for (int mt = 0; mt < 4; ++mt)
#pragma unroll
        for (int nt = 0; nt < 4; ++nt)
          acc[mt][nt] = __builtin_amdgcn_mfma_f32_16x16x32_bf16(af[mt], bfv[nt], acc[mt][nt], 0, 0, 0);
    }
  }

  if (MODE == 0) {
    const int sec = bn >> 3;                       // 0:q 1:k 2:v  (block-uniform)
    const int h0 = ((bn & 7) << 1) + (wc >> 6);    // head (wave-uniform)
    const float qsc = (sec == 0) ? 0.125f : 1.0f;
    float wv[4], bvv[4];
    if (sec < 2) {
      const float* wp_ = sec ? kn_w : qn_w;
      const float* bp_ = sec ? kn_b : qn_b;
#pragma unroll
      for (int nt = 0; nt < 4; ++nt) {
        wv[nt] = wp_[nt * 16 + lrow];
        bvv[nt] = bp_[nt * 16 + lrow];
      }
    }
    unsigned short* qk_dst = sec ? kws : qws;
#pragma unroll
    for (int mt = 0; mt < 4; ++mt)
#pragma unroll
      for (int r = 0; r < 4; ++r) {
        int grow = bm * 128 + wr + mt * 16 + lk * 4 + r;
        int b = grow / 65, nn = grow - b * 65;     // const div -> magic mul
        int bh = b * HEADS + h0;
        if (sec < 2) {
          // fused LayerNorm over the 64 head elems (4 nt-regs x 16 lrow lanes)
          float s = 0.f, s2 = 0.f;
#pragma unroll
          for (int nt = 0; nt < 4; ++nt) {
            float f = acc[mt][nt][r];
            s += f; s2 += f * f;
          }
          s += __shfl_xor(s, 1); s2 += __shfl_xor(s2, 1);
          s += __shfl_xor(s, 2); s2 += __shfl_xor(s2, 2);
          s += __shfl_xor(s, 4); s2 += __shfl_xor(s2, 4);
          s += __shfl_xor(s, 8); s2 += __shfl_xor(s2, 8);
          float mu = s * 0.015625f;
          float rstd = rsqrtf(s2 * 0.015625f - mu * mu + 1e-5f);
          size_t base = ((size_t)bh * 65 + nn) * 64;
#pragma unroll
          for (int nt = 0; nt < 4; ++nt)
            qk_dst[base + nt * 16 + lrow] =
                f2bf(((acc[mt][nt][r] - mu) * rstd * wv[nt] + bvv[nt]) * qsc);
        } else {
#pragma unroll
          for (int nt = 0; nt < 4; ++nt)
            vws[((size_t)bh * 64 + nt * 16 + lrow) * 80 + nn] = f2bf(acc[mt][nt][r]);
        }
      }
  } else {
    const size_t cb = (size_t)bn * 128 + wc + lrow;
#pragma unroll
    for (int mt = 0; mt < 4; ++mt)
#pragma unroll
      for (int r = 0; r < 4; ++r) {
        float* rp = outp + (size_t)(bm * 128 + wr + mt * 16 + lk * 4 + r) * 1024 + cb;
#pragma unroll
        for (int nt = 0; nt < 4; ++nt) rp[nt * 16] = acc[mt][nt][r];
      }
  }
}

// ---------------- attention per (b,h): S=qk^T, softmax, O=PV ----------------
// q,k already LayerNormed (+q scale) by gemm0. Staging via global_load_lds.
__global__ __launch_bounds__(256) void attn_kernel(
    const unsigned short* __restrict__ qws, const unsigned short* __restrict__ kws,
    const unsigned short* __restrict__ vws,
    const float* __restrict__ bias, const float* __restrict__ bias_scale,
    unsigned short* __restrict__ aws) {
  __shared__ unsigned short qk_s[2 * 80 * 64];  // q rows 0..79, k rows 0..79 (swizzled chunks)
  __shared__ unsigned short v_s[64 * 128];      // vT rows d, 16 chunks (swizzled)
  __shared__ unsigned short p_s[80 * 128];
  const int tid = threadIdx.x;
  const int wid = tid >> 6;
  const int bh = blockIdx.x;
  const int b = bh >> 4, h = bh & 15;
  const size_t qbase = (size_t)bh * 65 * 64;
  const size_t vbase = (size_t)bh * 64 * 80;

  // zero all of p_s (PV reads swizzled chunks up to slot 15)
  {
    bf16x8 z = {};
    for (int i = tid; i < 1280; i += 256) *(bf16x8*)&p_s[i * 8] = z;
    // zero q/k pad rows 65..79
    if (tid < 240) {
      int half = tid >= 120 ? 1 : 0;
      int cc = tid - half * 120;                // 0..119
      int row = 65 + (cc >> 3), k8 = cc & 7;
      *(bf16x8*)&qk_s[half * 5120 + row * 64 + k8 * 8] = z;
    }
  }

  // async stage q,k rows 0..63 (512 chunks each, 2 rounds of 256)
#pragma unroll
  for (int it = 0; it < 2; ++it) {
    int ci = it * 256 + tid;
    int row = ci >> 3, k8s = ci & 7;
    int k8 = k8s ^ (row & 7);
    __builtin_amdgcn_global_load_lds(
        (const __attribute__((address_space(1))) unsigned int*)(qws + qbase + row * 64 + k8 * 8),
        (__attribute__((address_space(3))) unsigned int*)qk_s + (size_t)(it * 256 + wid * 64) * 4,
        16, 0, 0);
    __builtin_amdgcn_global_load_lds(
        (const __attribute__((address_space(1))) unsigned int*)(kws + qbase + row * 64 + k8 * 8),
        (__attribute__((address_space(3))) unsigned int*)qk_s + (size_t)(640 + it * 256 + wid * 64) * 4,
        16, 0, 0);
  }
  // row 64 (8 chunks each) via plain copy; row&7==0 so no swizzle change
  if (tid < 8) {
    bf16x8 tq = *(const bf16x8*)&qws[qbase + 64 * 64 + tid * 8];
    *(bf16x8*)&qk_s[64 * 64 + tid * 8] = tq;
  } else if (tid < 16) {
    int t = tid - 8;
    bf16x8 tk = *(const bf16x8*)&kws[qbase + 64 * 64 + t * 8];
    *(bf16x8*)&qk_s[5120 + 64 * 64 + t * 8] = tk;
  }
  // async stage vT: 64 rows x 16 chunks = 1024 chunks (chunks >=10 read adjacent
  // garbage; they only ever multiply exact-zero P columns)
#pragma unroll
  for (int it = 0; it < 4; ++it) {
    int ci = it * 256 + tid;
    int d = ci >> 4, cs = ci & 15;
    int c = cs ^ (d & 7);
    __builtin_amdgcn_global_load_lds(
        (const __attribute__((address_space(1))) unsigned int*)(vws + vbase + d * 80 + c * 8),
        (__attribute__((address_space(3))) unsigned int*)v_s + (size_t)(it * 256 + wid * 64) * 4,
        16, 0, 0);
  }
  __syncthreads();

  const int lane = tid & 63;
  const int lrow = lane & 15, lk = lane >> 4;
  const float bsc = *bias_scale;
  const unsigned short* q_s = qk_s;
  const unsigned short* k_s = qk_s + 5120;

  // S = q@k^T (+bias, mask) then softmax per row; strips of 16 rows over waves
  for (int s = wid; s < 5; s += 4) {
    f32x4 accs[5] = {};
#pragma unroll
    for (int kk = 0; kk < 2; ++kk) {
      const int cpos = (kk * 4 + lk) ^ (lrow & 7);
      bf16x8 af = *(const bf16x8*)&q_s[(s * 16 + lrow) * 64 + cpos * 8];
#pragma unroll
      for (int nt = 0; nt < 5; ++nt) {
        bf16x8 bv = *(const bf16x8*)&k_s[(nt * 16 + lrow) * 64 + cpos * 8];
        accs[nt] = __builtin_amdgcn_mfma_f32_16x16x32_bf16(af, bv, accs[nt], 0, 0, 0);
      }
    }
#pragma unroll
    for (int r = 0; r < 4; ++r) {
      int row = s * 16 + lk * 4 + r;
      int brow = row > 64 ? 64 : row;
      float vals[5];
#pragma unroll
      for (int nt = 0; nt < 5; ++nt) {
        int col = nt * 16 + lrow;
        float v = accs[nt][r];
        if (col < 65) v += bias[((size_t)h * 65 + brow) * 65 + col] * bsc;
        else v = -1e30f;
        vals[nt] = v;
      }
      float m = vals[0];
#pragma unroll
      for (int nt = 1; nt < 5; ++nt) m = fmaxf(m, vals[nt]);
      m = fmaxf(m, __shfl_xor(m, 1)); m = fmaxf(m, __shfl_xor(m, 2));
      m = fmaxf(m, __shfl_xor(m, 4)); m = fmaxf(m, __shfl_xor(m, 8));
      float ssum = 0.f;
#pragma unroll
      for (int nt = 0; nt < 5; ++nt) { vals[nt] = __expf(vals[nt] - m); ssum += vals[nt]; }
      ssum += __shfl_xor(ssum, 1); ssum += __shfl_xor(ssum, 2);
      ssum += __shfl_xor(ssum, 4); ssum += __shfl_xor(ssum, 8);
      float inv = 1.0f / ssum;
#pragma unroll
      for (int nt = 0; nt < 5; ++nt) {
        int col = nt * 16 + lrow;
        p_s[row * 128 + ((col >> 3) ^ (row & 7)) * 8 + (col & 7)] = f2bf(vals[nt] * inv);
      }
    }
  }
  __syncthreads();

  // O = P @ V  (k-dim 96 with zero pad), write [B*N, 1024] bf16
  const size_t obase = (size_t)b * 65 * 1024 + h * 64;
  for (int s = wid; s < 5; s += 4) {
    f32x4 acco[4] = {};
#pragma unroll
    for (int kk = 0; kk < 3; ++kk) {
      const int cpos = (kk * 4 + lk) ^ (lrow & 7);
      bf16x8 af = *(const bf16x8*)&p_s[(s * 16 + lrow) * 128 + cpos * 8];
#pragma unroll
      for (int nt = 0; nt < 4; ++nt) {
        bf16x8 bv = *(const bf16x8*)&v_s[(nt * 16 + lrow) * 128 + cpos * 8];
        acco[nt] = __builtin_amdgcn_mfma_f32_16x16x32_bf16(af, bv, acco[nt], 0, 0, 0);
      }
    }
#pragma unroll
    for (int r = 0; r < 4; ++r) {
      int row = s * 16 + lk * 4 + r;
      if (row < 65) {
#pragma unroll
        for (int nt = 0; nt < 4; ++nt)
          aws[obase + (size_t)row * 1024 + nt * 16 + lrow] = f2bf(acco[nt][r]);
      }
    }
  }
}

extern "C" void kernel_launch(void* const* d_in, const int* in_sizes, int n_in,
                              void* d_out, int out_size, void* d_ws, size_t ws_size,
                              hipStream_t stream) {
  const float* x     = (const float*)d_in[0];
  const float* wqkv  = (const float*)d_in[1];
  const float* wproj = (const float*)d_in[2];
  const float* qn_w  = (const float*)d_in[3];
  const float* qn_b  = (const float*)d_in[4];
  const float* kn_w  = (const float*)d_in[5];
  const float* kn_b  = (const float*)d_in[6];
  const float* bias  = (const float*)d_in[7];
  const float* bsc   = (const float*)d_in[8];
  float* out = (float*)d_out;

  unsigned short* xb  = (unsigned short*)d_ws;
  unsigned short* wqb = xb + NX;
  unsigned short* wpb = wqb + NQW;
  unsigned short* qws = wpb + NPW;
  unsigned short* kws = qws + 34078720UL;          // BH*65*64
  unsigned short* vws = kws + 34078720UL;
  unsigned short* aws = vws + 41943040UL;          // BH*64*80

  cast3_kernel<<<37376, 256, 0, stream>>>(x, wqkv, wproj, xb, wqb, wpb);
  gemm_bt_kernel<0><<<dim3(24, 260), 256, 0, stream>>>(xb, wqb, qws, kws, vws, nullptr,
                                                       qn_w, qn_b, kn_w, kn_b);
  attn_kernel<<<8192, 256, 0, stream>>>(qws, kws, vws, bias, bsc, aws);
  gemm_bt_kernel<1><<<dim3(8, 260), 256, 0, stream>>>(aws, wpb, nullptr, nullptr, nullptr, out,
                                                      nullptr, nullptr, nullptr, nullptr);
}